// Round 4
// baseline (282.165 us; speedup 1.0000x reference)
//
#include <hip/hip_runtime.h>
#include <stdint.h>
#include <stddef.h>

// ---------------------------------------------------------------------------
// 4 GAE encoders, fp16 MFMA. All GEMMs: C = A @ B^T (A:[M][lda], B:[N][ldb]).
//   prep  : X1,X2 -> fp16 padded Xh  +  12 weights -> fp16 transposed (LDS tiles)
//   fused : adjacency fp32->fp16 cast  ∥  step1 T1 = tanh(W1t @ Xh^T) direct
//   step2 : Z1 = reduce( Adj @ T1^T )          (split-K 4)
//   step3 : T2 = tanh( W2t @ Z1^T )            (direct)
//   step4 : Z2 = reduce( Adj @ T2^T )          (split-K 8)
//   step5 : T3 = W3t @ Z2^T                    (direct)
//   step6 : Z3 = reduce( Adj @ T3^T )          (split-K 8)
//   step7 : OUT = sigmoid( Z3 @ Z3^T ), K=64   (fp32, LDS-repacked stores)
// Adj fp16 copies AND fp32 split-K partials live in d_out (75.5+50.3 < 144 MB;
// both dead before step7 overwrites d_out).
// ---------------------------------------------------------------------------

typedef __attribute__((ext_vector_type(8))) _Float16 half8;
typedef __attribute__((ext_vector_type(4))) float f32x4;

#define PAD 3072
#define MR  3000
#define ADJ_STRIDE ((size_t)PAD * PAD)

static __device__ __forceinline__ void async_cp16(const _Float16* g, _Float16* l) {
    __builtin_amdgcn_global_load_lds((const __attribute__((address_space(1))) void*)g,
                                     (__attribute__((address_space(3))) void*)l, 16, 0, 0);
}

// ---------------- prep: X cast + weight transpose (LDS 64x64 tiles) --------
struct PrepArgs {
    const float* X[2]; _Float16* Xh;
    const float* Wsrc[12];          // [enc*3 + layer]
    _Float16* Wdst[3];              // W1t, W2t, W3t bases
};

__global__ __launch_bounds__(256) void prep(PrepArgs p) {
    __shared__ _Float16 lt[64 * 64];
    const int b = blockIdx.x;
    const int t = threadIdx.x;
    if (b < 4608) {
        // X cast: fp32 [3000][3000] -> fp16 [3072][3072] zero-padded
        const int which = b / 2304;
        const int idx = (b - which * 2304) * 256 + t;
        const int row = idx / 192;
        const int c0  = (idx - row * 192) * 16;
        const float* sp = p.X[which] + (size_t)row * MR + c0;
        _Float16* d = p.Xh + (size_t)which * ADJ_STRIDE + (size_t)row * PAD + c0;
        half8 h0, h1;
        const bool rok = row < MR;
        if (rok && c0 < MR) {
            f32x4 v0 = __builtin_nontemporal_load((const f32x4*)sp);
            f32x4 v1 = __builtin_nontemporal_load((const f32x4*)(sp + 4));
            #pragma unroll
            for (int j = 0; j < 4; ++j) { h0[j] = (_Float16)v0[j]; h0[4 + j] = (_Float16)v1[j]; }
        } else {
            #pragma unroll
            for (int j = 0; j < 8; ++j) h0[j] = (_Float16)0.f;
        }
        if (rok && c0 + 8 < MR) {
            f32x4 v2 = __builtin_nontemporal_load((const f32x4*)(sp + 8));
            f32x4 v3 = __builtin_nontemporal_load((const f32x4*)(sp + 12));
            #pragma unroll
            for (int j = 0; j < 4; ++j) { h1[j] = (_Float16)v2[j]; h1[4 + j] = (_Float16)v3[j]; }
        } else {
            #pragma unroll
            for (int j = 0; j < 8; ++j) h1[j] = (_Float16)0.f;
        }
        *(half8*)d = h0;
        *(half8*)(d + 8) = h1;
    } else {
        // weight transpose-cast: src [fi][fo] fp32 -> dst [fo_pad][ldk] fp16
        // per-enc tiles: W1 48x4=192, W2 4x2=8, W3 2x2=4  (204/enc, 816 total)
        const int b2  = b - 4608;
        const int enc = b2 / 204;
        int rem = b2 - enc * 204;
        const float* src; _Float16* dst; int fi, fo, ldk, kt, rt;
        if (rem < 192) {
            src = p.Wsrc[enc * 3 + 0]; dst = p.Wdst[0] + (size_t)enc * 256 * PAD;
            fi = MR; fo = 256; ldk = PAD; kt = rem >> 2; rt = rem & 3;
        } else if (rem < 200) {
            rem -= 192;
            src = p.Wsrc[enc * 3 + 1]; dst = p.Wdst[1] + (size_t)enc * 128 * 256;
            fi = 256; fo = 128; ldk = 256; kt = rem >> 1; rt = rem & 1;
        } else {
            rem -= 200;
            src = p.Wsrc[enc * 3 + 2]; dst = p.Wdst[2] + (size_t)enc * 128 * 128;
            fi = 128; fo = 64; ldk = 128; kt = rem >> 1; rt = rem & 1;
        }
        const int k0 = kt * 64, r0 = rt * 64;
        {
            const int kr = t >> 2, cc = (t & 3) << 4;
            const int gk = k0 + kr;
            const bool kok = gk < fi;
            #pragma unroll
            for (int j = 0; j < 16; ++j) {
                const int gr = r0 + cc + j;
                const float v = (kok && gr < fo) ? src[(size_t)gk * fo + gr] : 0.f;
                lt[(cc + j) * 64 + kr] = (_Float16)v;
            }
        }
        __syncthreads();
        {
            const int rr = t >> 2, kk = (t & 3) << 4;
            half8 a  = *(half8*)&lt[rr * 64 + kk];
            half8 bb = *(half8*)&lt[rr * 64 + kk + 8];
            _Float16* dp = dst + (size_t)(r0 + rr) * ldk + k0 + kk;
            *(half8*)dp = a;
            *(half8*)(dp + 8) = bb;
        }
    }
}

// ---------------- GEMM body: C = A @ B^T ----------------
struct GArgs {
    const _Float16* Aall; size_t aStride; int aMask;
    const _Float16* Ball; size_t bStride; int bMask;
    void* Call; size_t cStride;
    int M, Ncols, Kp, lda, ldb, ldc, mBound, nBound;
};

// OMODE: 0 = direct fp16 (opt tanh via ACT), 2 = fp32 sigmoid (LDS repack),
//        3 = fp32 raw partial (LDS repack).  S = split-K factor.
template<int ACT, int OMODE, int S>
static __device__ __forceinline__
void gemm_body(const GArgs& ga, int bx, int by, int bz, _Float16* smem)
{
    _Float16* As = smem;
    _Float16* Bs = smem + 8192;

    const int z   = bz;
    const int e   = z / S;
    const int ksl = z - e * S;
    const int Kslice = ga.Kp / S;
    const int kbase  = ksl * Kslice;

    const _Float16* A = ga.Aall + (size_t)(e & ga.aMask) * ga.aStride;
    const _Float16* B = ga.Ball + (size_t)(e & ga.bMask) * ga.bStride;

    const int tm = bx * 128;
    const int tn = by * 128;
    const int t    = threadIdx.x;
    const int lane = t & 63;
    const int w    = t >> 6;
    const int wm   = (w >> 1) * 64;
    const int wn   = (w & 1) * 64;
    const int lr   = lane & 15;
    const int lg   = lane >> 4;

    f32x4 acc[4][4];
    const f32x4 zero = {0.f, 0.f, 0.f, 0.f};
    #pragma unroll
    for (int i = 0; i < 4; ++i)
        #pragma unroll
        for (int j = 0; j < 4; ++j) acc[i][j] = zero;

    const int nkt = Kslice >> 6;
    for (int kt = 0; kt < nkt; ++kt) {
        const int k0 = kbase + (kt << 6);
        #pragma unroll
        for (int i = 0; i < 4; ++i) {
            const int c = t + i * 256;
            const int row = c >> 3, slot = c & 7;
            const int ss = slot ^ (row & 7);
            async_cp16(A + (size_t)(tm + row) * ga.lda + k0 + ss * 8, &As[c * 8]);
        }
        #pragma unroll
        for (int i = 0; i < 4; ++i) {
            const int c = t + i * 256;
            const int row = c >> 3, slot = c & 7;
            const int ss = slot ^ (row & 7);
            async_cp16(B + (size_t)(tn + row) * ga.ldb + k0 + ss * 8, &Bs[c * 8]);
        }
        __syncthreads();

        #pragma unroll
        for (int ks = 0; ks < 2; ++ks) {
            half8 af[4], bf[4];
            #pragma unroll
            for (int mi = 0; mi < 4; ++mi) {
                const int ra = wm + mi * 16 + lr;
                const int s  = (ks * 4 + lg) ^ (ra & 7);
                af[mi] = *(const half8*)((const char*)As + ra * 128 + s * 16);
            }
            #pragma unroll
            for (int ni = 0; ni < 4; ++ni) {
                const int rb = wn + ni * 16 + lr;
                const int s  = (ks * 4 + lg) ^ (rb & 7);
                bf[ni] = *(const half8*)((const char*)Bs + rb * 128 + s * 16);
            }
            #pragma unroll
            for (int mi = 0; mi < 4; ++mi)
                #pragma unroll
                for (int ni = 0; ni < 4; ++ni)
                    acc[mi][ni] = __builtin_amdgcn_mfma_f32_16x16x32_f16(
                        af[mi], bf[ni], acc[mi][ni], 0, 0, 0);
        }
        __syncthreads();
    }

    // epilogue. D layout: col = lane&15, row = 4*(lane>>4)+reg (m89-verified).
    if (OMODE == 0) {
        _Float16* C = (_Float16*)ga.Call + (size_t)e * ga.cStride;
        #pragma unroll
        for (int mi = 0; mi < 4; ++mi)
            #pragma unroll
            for (int rr = 0; rr < 4; ++rr) {
                const int m = tm + wm + mi * 16 + lg * 4 + rr;
                #pragma unroll
                for (int ni = 0; ni < 4; ++ni) {
                    const int n = tn + wn + ni * 16 + lr;
                    float x = acc[mi][ni][rr];
                    if (ACT) x = tanhf(x);
                    const bool ok = (m < ga.M) && (n < ga.Ncols);
                    C[(size_t)m * ga.ldc + n] = ok ? (_Float16)x : (_Float16)0.f;
                }
            }
    } else {
        // fp32 LDS-repack epilogue: per-wave 32x64 staging, float4 stores.
        float* Cp = (float*)ga.Call + (size_t)(OMODE == 3 ? z : e) * ga.cStride;
        float* ep = (float*)smem + w * 2048;   // 32 rows x 64 cols
        #pragma unroll
        for (int hs = 0; hs < 2; ++hs) {
            __syncthreads();
            #pragma unroll
            for (int mi2 = 0; mi2 < 2; ++mi2)
                #pragma unroll
                for (int ni = 0; ni < 4; ++ni)
                    #pragma unroll
                    for (int rr = 0; rr < 4; ++rr) {
                        const int row = mi2 * 16 + lg * 4 + rr;
                        const int col = ni * 16 + lr;
                        const int sw  = (((row ^ (row >> 2)) & 3) << 4);
                        ep[row * 64 + (col ^ sw)] = acc[hs * 2 + mi2][ni][rr];
                    }
            __syncthreads();
            #pragma unroll
            for (int r2 = 0; r2 < 8; ++r2) {
                const int row = r2 * 4 + (lane >> 4);
                const int c4  = (lane & 15) * 4;
                const int sw  = (((row ^ (row >> 2)) & 3) << 4);
                f32x4 v = *(const f32x4*)&ep[row * 64 + (c4 ^ sw)];
                const int gm = tm + wm + hs * 32 + row;
                const int gn = tn + wn + c4;
                if (gm < ga.mBound && gn < ga.nBound) {
                    if (OMODE == 2) {
                        #pragma unroll
                        for (int j = 0; j < 4; ++j)
                            v[j] = 1.0f / (1.0f + __expf(-v[j]));
                    }
                    *(f32x4*)&Cp[(size_t)gm * ga.ldc + gn] = v;
                }
            }
        }
    }
}

template<int ACT, int OMODE, int S>
__global__ __launch_bounds__(256, 2)
void gemm_bt(GArgs ga) {
    __shared__ _Float16 smem[16384];
    gemm_body<ACT, OMODE, S>(ga, blockIdx.x, blockIdx.y, blockIdx.z, smem);
}

// ------- fused: step1 (192 GEMM blocks, S=1, tanh) + adjacency cast --------
struct Adj4 { const float* src[4]; };

__global__ __launch_bounds__(256, 2)
void fused_s1(GArgs ga, Adj4 a4, _Float16* __restrict__ adst)
{
    __shared__ _Float16 smem[16384];
    const int b = blockIdx.x;
    if (b < 192) {
        const int e   = b / 48;            // encoder
        const int rem = b - e * 48;
        gemm_body<1, 0, 1>(ga, rem & 1, rem >> 1, e, smem);
    } else {
        const int cb  = b - 192;
        const int zz  = cb / 2304;
        const int idx = (cb - zz * 2304) * 256 + threadIdx.x;
        const int row = idx / 192;
        const int u   = idx - row * 192;
        const int c0  = u * 16;
        const float* sp = a4.src[zz] + (size_t)row * MR + c0;
        _Float16* d = adst + (size_t)zz * ADJ_STRIDE + (size_t)row * PAD + c0;
        half8 h0, h1;
        const bool rok = row < MR;
        if (rok && c0 < MR) {
            f32x4 v0 = __builtin_nontemporal_load((const f32x4*)sp);
            f32x4 v1 = __builtin_nontemporal_load((const f32x4*)(sp + 4));
            #pragma unroll
            for (int j = 0; j < 4; ++j) { h0[j] = (_Float16)v0[j]; h0[4 + j] = (_Float16)v1[j]; }
        } else {
            #pragma unroll
            for (int j = 0; j < 8; ++j) h0[j] = (_Float16)0.f;
        }
        if (rok && c0 + 8 < MR) {
            f32x4 v2 = __builtin_nontemporal_load((const f32x4*)(sp + 8));
            f32x4 v3 = __builtin_nontemporal_load((const f32x4*)(sp + 12));
            #pragma unroll
            for (int j = 0; j < 4; ++j) { h1[j] = (_Float16)v2[j]; h1[4 + j] = (_Float16)v3[j]; }
        } else {
            #pragma unroll
            for (int j = 0; j < 8; ++j) h1[j] = (_Float16)0.f;
        }
        *(half8*)d = h0;
        *(half8*)(d + 8) = h1;
    }
}

// ---------------- split-K reduce: out = sum_s P[s] in fp16 ----------
template<int S>
__global__ __launch_bounds__(256)
void reduce_k(const float* __restrict__ P, _Float16* __restrict__ out, size_t region)
{
    const size_t e    = blockIdx.y;
    const size_t base = (size_t)(blockIdx.x * 256 + threadIdx.x) * 8;
    const float* p0 = P + e * S * region + base;
    f32x4 s0 = {0.f, 0.f, 0.f, 0.f}, s1 = s0;
    #pragma unroll
    for (int s = 0; s < S; ++s) {
        const float* p = p0 + (size_t)s * region;
        s0 += *(const f32x4*)p;
        s1 += *(const f32x4*)(p + 4);
    }
    half8 h;
    #pragma unroll
    for (int j = 0; j < 8; ++j)
        h[j] = (_Float16)((j < 4) ? s0[j] : s1[j - 4]);
    *(half8*)(out + e * region + base) = h;
}

// ---------------- launcher ----------------
extern "C" void kernel_launch(void* const* d_in, const int* in_sizes, int n_in,
                              void* d_out, int out_size, void* d_ws, size_t ws_size,
                              hipStream_t stream)
{
    const size_t R1 = 786432;   // 256*3072 and 3072*256
    const size_t R2 = 393216;   // 128*3072 and 3072*128

    // d_out layout: [4 x fp16 Adj (75.5 MB)] [fp32 Part (50.3 MB)]
    _Float16* Adj  = (_Float16*)d_out;
    float*    Part = (float*)(Adj + 4 * ADJ_STRIDE);

    _Float16* hb = (_Float16*)d_ws;
    size_t off = 0;
    auto alloc = [&](size_t elems) { _Float16* p = hb + off; off += elems; return p; };
    _Float16* Xh  = alloc(2 * ADJ_STRIDE);
    _Float16* T1  = alloc(4 * R1);
    _Float16* Z1  = alloc(4 * R1);
    _Float16* T2  = alloc(4 * R2);
    _Float16* Z2  = alloc(4 * R2);
    _Float16* T3  = alloc(4 * R2);
    _Float16* Z3  = alloc(4 * R2);
    _Float16* W1t = alloc(4ull * 256 * PAD);
    _Float16* W2t = alloc(4ull * 128 * 256);
    _Float16* W3t = alloc(4ull * 128 * 128);

    // prep: X cast + weight transpose
    PrepArgs pa;
    pa.X[0] = (const float*)d_in[0];
    pa.X[1] = (const float*)d_in[1];
    pa.Xh = Xh;
    for (int enc = 0; enc < 4; ++enc)
        for (int li = 0; li < 3; ++li)
            pa.Wsrc[enc * 3 + li] = (const float*)d_in[6 + enc * 3 + li];
    pa.Wdst[0] = W1t; pa.Wdst[1] = W2t; pa.Wdst[2] = W3t;
    prep<<<dim3(5424, 1, 1), 256, 0, stream>>>(pa);

    const int BIG = 1 << 30;

    // fused: step1 T1 = tanh(W1t @ Xh^T)  (M=256 N=3072 K=3072, S=1, direct)
    //        + adjacency fp32->fp16 cast (9216 blocks)
    GArgs g1 = { W1t, (size_t)256 * PAD, 3, Xh, ADJ_STRIDE, 1,
                 T1, R1, 256, PAD, PAD, PAD, PAD, PAD, BIG, BIG };
    Adj4 a4;
    for (int i = 0; i < 4; ++i) a4.src[i] = (const float*)d_in[2 + i];
    fused_s1<<<dim3(9408, 1, 1), 256, 0, stream>>>(g1, a4, Adj);

    // step2: P = Adj @ T1^T  M=3072 N=256 K=3072, S=4
    GArgs g2 = { Adj, ADJ_STRIDE, 3, T1, R1, 3,
                 Part, R1, PAD, 256, PAD, PAD, PAD, 256, BIG, BIG };
    gemm_bt<0, 3, 4><<<dim3(24, 2, 16), 256, 0, stream>>>(g2);
    reduce_k<4><<<dim3(384, 4, 1), 256, 0, stream>>>(Part, Z1, R1);

    // step3: T2 = tanh(W2t @ Z1^T)  M=128 N=3072 K=256, direct
    GArgs g3 = { W2t, (size_t)128 * 256, 3, Z1, R1, 3,
                 T2, R2, 128, PAD, 256, 256, 256, PAD, BIG, BIG };
    gemm_bt<1, 0, 1><<<dim3(1, 24, 4), 256, 0, stream>>>(g3);

    // step4: P = Adj @ T2^T  M=3072 N=128 K=3072, S=8
    GArgs g4 = { Adj, ADJ_STRIDE, 3, T2, R2, 3,
                 Part, R2, PAD, 128, PAD, PAD, PAD, 128, BIG, BIG };
    gemm_bt<0, 3, 8><<<dim3(24, 1, 32), 256, 0, stream>>>(g4);
    reduce_k<8><<<dim3(192, 4, 1), 256, 0, stream>>>(Part, Z2, R2);

    // step5: T3 = W3t @ Z2^T  M=128 N=3072 K=128, direct
    GArgs g5 = { W3t, (size_t)128 * 128, 3, Z2, R2, 3,
                 T3, R2, 128, PAD, 128, 128, 128, PAD, BIG, BIG };
    gemm_bt<0, 0, 1><<<dim3(1, 24, 4), 256, 0, stream>>>(g5);

    // step6: P = Adj @ T3^T  M=3072 N=128 K=3072, S=8
    GArgs g6 = { Adj, ADJ_STRIDE, 3, T3, R2, 3,
                 Part, R2, PAD, 128, PAD, PAD, PAD, 128, BIG, BIG };
    gemm_bt<0, 3, 8><<<dim3(24, 1, 32), 256, 0, stream>>>(g6);
    reduce_k<8><<<dim3(192, 4, 1), 256, 0, stream>>>(Part, Z3, R2);

    // step7: OUT = sigmoid(Z3 @ Z3^T)  M=N=3000 K=64 (cols 64..127 of Z3 zero)
    GArgs g7 = { Z3, R2, 3, Z3, R2, 3,
                 d_out, (size_t)MR * MR, MR, MR, 64, 128, 128, MR, MR, MR };
    gemm_bt<0, 2, 1><<<dim3(24, 24, 4), 256, 0, stream>>>(g7);
}